// Round 12
// baseline (948.774 us; speedup 1.0000x reference)
//
#include <hip/hip_runtime.h>
#include <math.h>

#define NLV 16
#define TBL_SIZE (1u << 19)
#define TBL_MASK (TBL_SIZE - 1u)
#define NBINS 32768
#define QSCALE 2097152.0f   // 2^21
#define QINV   (1.0f / 2097152.0f)

// workspace float offsets (weights block, also used by fallback)
#define W1_OFF 0      // [64][35] row-major, weight-normed (f32)
#define B1_OFF 2240   // [64]
#define W2_OFF 2304   // [64]
#define B2_OFF 2368   // [1]
#define WREG   2432   // floats reserved (9728 B, 16B-aligned)

typedef __attribute__((ext_vector_type(4))) float f32x4;
typedef __attribute__((ext_vector_type(8))) short bf16x8;
typedef __attribute__((ext_vector_type(2))) unsigned int u32x2;

struct LP {
    float scale[NLV];
    unsigned int res[NLV];
};

__device__ __forceinline__ unsigned int pack_bf16(float a, float b) {
    unsigned int ua = __float_as_uint(a);
    ua += 0x7fffu + ((ua >> 16) & 1u);           // RNE
    unsigned int ub = __float_as_uint(b);
    ub += 0x7fffu + ((ub >> 16) & 1u);
    return (ua >> 16) | (ub & 0xffff0000u);
}

__device__ __forceinline__ unsigned short bf16_rne(float x) {
    unsigned int u = __float_as_uint(x);
    u += 0x7fffu + ((u >> 16) & 1u);
    return (unsigned short)(u >> 16);
}

// x = hi + r exactly (hi = truncated-bf16 of x); lo = rne(r)
__device__ __forceinline__ void split_bf16(float x, unsigned short& hi, unsigned short& lo) {
    unsigned int u = __float_as_uint(x);
    hi = (unsigned short)(u >> 16);
    float r = x - __uint_as_float(u & 0xffff0000u);
    lo = bf16_rne(r);
}

__device__ __forceinline__ uint2 pack_pt(float px, float py, float pz) {
    unsigned int qx = (unsigned int)fminf(px * QSCALE, 2097151.0f);
    unsigned int qy = (unsigned int)fminf(py * QSCALE, 2097151.0f);
    unsigned int qz = (unsigned int)fminf(pz * QSCALE, 2097151.0f);
    uint2 r;
    r.x = qx | (qy << 21);
    r.y = (qy >> 11) | (qz << 10);
    return r;
}

__device__ __forceinline__ void unpack_pt(uint2 s, float& px, float& py, float& pz) {
    unsigned int qx = s.x & 0x1FFFFFu;
    unsigned int qy = (s.x >> 21) | ((s.y & 0x3FFu) << 11);
    unsigned int qz = (s.y >> 10) & 0x1FFFFFu;
    px = (float)qx * QINV;
    py = (float)qy * QINV;
    pz = (float)qz * QINV;
}

// merged x-pair trilinear gather for one level (dense or hashed)
__device__ __forceinline__ void gather_level(
    const unsigned int* __restrict__ tl, bool dense, unsigned int r, float scale,
    float px, float py, float pz, float& f0, float& f1) {
    float fx = fmaf(px, scale, 0.5f);
    float fy = fmaf(py, scale, 0.5f);
    float fz = fmaf(pz, scale, 0.5f);
    float bx = floorf(fx), by = floorf(fy), bz = floorf(fz);
    float wx = fx - bx, wy = fy - by, wz = fz - bz;
    unsigned int ix = (unsigned int)bx;
    unsigned int iy = (unsigned int)by;
    unsigned int iz = (unsigned int)bz;
    f0 = 0.f; f1 = 0.f;
    float omwx = 1.f - wx;
#pragma unroll
    for (int cyz = 0; cyz < 4; ++cyz) {
        unsigned int qy = cyz >> 1, qz = cyz & 1;
        unsigned int cy = iy + qy, cz = iz + qz;
        unsigned int i0, i1;
        if (dense) {
            i0 = ix + cy * r + cz * r * r;
            i1 = i0 + 1;
        } else {
            unsigned int ryz = (cy * 2654435761u) ^ (cz * 805459861u);
            i0 = (ix ^ ryz) & TBL_MASK;
            i1 = ((ix + 1u) ^ ryz) & TBL_MASK;
        }
        unsigned int sel = i0 & 1u;
        uint2 e = *(const uint2*)(tl + (i0 & ~1u));
        unsigned int lo_bits = sel ? e.y : e.x;
        unsigned int hi_bits = sel ? e.x : e.y;
        if (i1 != (i0 ^ 1u)) hi_bits = tl[i1];   // predicated: only unmerged lanes issue

        float wrow = (qy ? wy : 1.f - wy) * (qz ? wz : 1.f - wz);
        float wlo = wrow * omwx, whi = wrow * wx;
        f0 = fmaf(wlo, __uint_as_float(lo_bits << 16), f0);
        f1 = fmaf(wlo, __uint_as_float(lo_bits & 0xffff0000u), f1);
        f0 = fmaf(whi, __uint_as_float(hi_bits << 16), f0);
        f1 = fmaf(whi, __uint_as_float(hi_bits & 0xffff0000u), f1);
    }
}

// block 0: weight-norm prep + MFMA B-matrix build; blocks 1..: zero hist
// K-order (u32 slot s <-> K=2s,2s+1):
//  slot0: c0,c1  slot1: c2,BIAS(=1)  slot2+l (l=0..15): Lf0,Lf1
//  slot18: c0lo,c1lo  slot19: c2lo,0  slot20+l (l=0..5): Lf0lo,Lf1lo  slots26..31: 0
__global__ __launch_bounds__(256) void prep_kernel(
    const float* __restrict__ v1, const float* __restrict__ g1,
    const float* __restrict__ b1, const float* __restrict__ v2,
    const float* __restrict__ g2, const float* __restrict__ b2,
    float* __restrict__ w, unsigned int* __restrict__ hist,
    unsigned short* __restrict__ Bh, unsigned short* __restrict__ Bl) {
    int bid = blockIdx.x;
    if (bid > 0) {
        int t = (bid - 1) * 256 + threadIdx.x;
        if (t < NBINS) hist[t] = 0;
        return;
    }
    if (threadIdx.x >= 64) return;
    int j = threadIdx.x;
    float wn[35];
    float s = 0.f;
#pragma unroll
    for (int k = 0; k < 35; ++k) { float x = v1[j * 35 + k]; s += x * x; }
    float sc = g1[j] / sqrtf(s);
#pragma unroll
    for (int k = 0; k < 35; ++k) {
        wn[k] = v1[j * 35 + k] * sc;
        w[W1_OFF + j * 35 + k] = wn[k];
    }
    float b1j = b1[j];
    w[B1_OFF + j] = b1j;
    float s2 = 0.f;
#pragma unroll
    for (int i2 = 0; i2 < 64; ++i2) { float x = v2[i2]; s2 += x * x; }
    w[W2_OFF + j] = v2[j] * (g2[0] / sqrtf(s2));
    if (j == 0) w[B2_OFF] = b2[0];

#pragma unroll
    for (int k = 0; k < 64; ++k) {
        float v = 0.f;
        if (k < 3) v = wn[k];
        else if (k == 3) v = b1j;
        else if (k < 36) v = wn[k - 1];
        else if (k < 39) v = wn[k - 36];
        else if (k == 39) v = 0.f;
        else if (k < 52) v = wn[k - 37];
        unsigned short hi, lo;
        split_bf16(v, hi, lo);
        Bh[j * 64 + k] = hi;
        Bl[j * 64 + k] = lo;
    }
}

__device__ __forceinline__ unsigned int bin_key(float px, float py, float pz) {
    unsigned int ix = (unsigned int)floorf(fmaf(px, 31.f, 0.5f));
    unsigned int iy = (unsigned int)floorf(fmaf(py, 31.f, 0.5f));
    unsigned int iz = (unsigned int)floorf(fmaf(pz, 31.f, 0.5f));
    ix = min(ix, 31u); iy = min(iy, 31u); iz = min(iz, 31u);
    return ix | (iy << 5) | (iz << 10);
}

// fused: table convert | bin count (disjoint outputs)
__global__ __launch_bounds__(256) void aux_kernel(
    const float* __restrict__ table, unsigned int* __restrict__ tbl4,
    unsigned int* __restrict__ hist, const float* __restrict__ points,
    int n, int cvt_blocks) {
    int bid = blockIdx.x;
    if (bid < cvt_blocks) {
        int t = bid * 256 + threadIdx.x;
        int total_pairs = NLV * TBL_SIZE / 2;
        if (t >= total_pairs) return;
        const float4 v = *(const float4*)(table + (size_t)t * 4);
        uint2 o;
        o.x = pack_bf16(v.x, v.y);
        o.y = pack_bf16(v.z, v.w);
        *(uint2*)(tbl4 + (size_t)t * 2) = o;
    } else {
        int i = (bid - cvt_blocks) * 256 + threadIdx.x;
        if (i >= n) return;
        unsigned int k = bin_key(points[3 * i], points[3 * i + 1], points[3 * i + 2]);
        atomicAdd(&hist[k], 1u);
    }
}

// single-block exclusive scan of 32768 bins
__global__ __launch_bounds__(1024) void scan_kernel(unsigned int* __restrict__ hist) {
    __shared__ unsigned int part[1024];
    int tid = threadIdx.x;
    int base = tid * 32;
    unsigned int s = 0;
#pragma unroll
    for (int k = 0; k < 32; ++k) s += hist[base + k];
    part[tid] = s;
    __syncthreads();
    for (int d = 1; d < 1024; d <<= 1) {
        unsigned int v = (tid >= d) ? part[tid - d] : 0u;
        __syncthreads();
        part[tid] += v;
        __syncthreads();
    }
    unsigned int run = part[tid] - s;
#pragma unroll
    for (int k = 0; k < 32; ++k) {
        unsigned int t = hist[base + k];
        hist[base + k] = run;
        run += t;
    }
}

__global__ __launch_bounds__(256) void scatter_kernel(const float* __restrict__ points,
                                                      unsigned int* __restrict__ hist,
                                                      uint2* __restrict__ spts,
                                                      unsigned int* __restrict__ sidx, int n) {
    int i = blockIdx.x * 256 + threadIdx.x;
    if (i >= n) return;
    float px = points[3 * i], py = points[3 * i + 1], pz = points[3 * i + 2];
    unsigned int k = bin_key(px, py, pz);
    unsigned int pos = atomicAdd(&hist[k], 1u);
    spts[pos] = pack_pt(px, py, pz);
    sidx[pos] = (unsigned int)i;
}

// one PAIR of fine hash levels per dispatch (4MB slab footprint = one XCD L2);
// shared point unpack, coalesced uint2 feat store
__global__ __launch_bounds__(256) void hashP_kernel(
    const uint2* __restrict__ spts, const unsigned int* __restrict__ tl0,
    const unsigned int* __restrict__ tl1, float scale0, float scale1,
    uint2* __restrict__ featp, int n) {
    int i = blockIdx.x * 256 + threadIdx.x;
    if (i >= n) return;
    float px, py, pz;
    unpack_pt(spts[i], px, py, pz);
    float a0, a1, b0, b1;
    gather_level(tl0, false, 0u, scale0, px, py, pz, a0, a1);
    gather_level(tl1, false, 0u, scale1, px, py, pz, b0, b1);
    u32x2 o;
    o.x = pack_bf16(a0, a1);
    o.y = pack_bf16(b0, b1);
    __builtin_nontemporal_store(o, (u32x2*)&featp[i]);
}

// coarse levels inline + paired fine feats -> LDS (swizzled) -> MFMA MLP
__global__ __launch_bounds__(256) void mlp2_kernel(
    const uint2* __restrict__ spts, const unsigned int* __restrict__ sidx,
    const unsigned int* __restrict__ tbl4, const uint2* __restrict__ featp,
    const float* __restrict__ w, const unsigned short* __restrict__ Bh,
    const unsigned short* __restrict__ Bl, float* __restrict__ out, LP lp, int n) {
    __shared__ unsigned int lds[4][64][32];     // 8KB per wave
    int lane = threadIdx.x & 63;
    int wid = threadIdx.x >> 6;
    int base = blockIdx.x * 256 + wid * 64;
    if (base >= n) return;
    int i = base + lane;
    int ic = (i < n) ? i : (n - 1);

    float px, py, pz;
    unpack_pt(spts[ic], px, py, pz);

    char* my = (char*)&lds[wid][0][0];
    int rowoff = lane * 128;
    int swz = (lane & 7) << 4;
#define WR_SLOT(s, v) *(unsigned int*)(my + rowoff + (((s) * 4) ^ swz)) = (v)

    {
        unsigned short h0, l0, h1, l1, h2, l2;
        split_bf16(px * 2.f - 1.f, h0, l0);
        split_bf16(py * 2.f - 1.f, h1, l1);
        split_bf16(pz * 2.f - 1.f, h2, l2);
        WR_SLOT(0, (unsigned)h0 | ((unsigned)h1 << 16));
        WR_SLOT(1, (unsigned)h2 | (0x3f80u << 16));      // bias slot = 1.0
        WR_SLOT(18, (unsigned)l0 | ((unsigned)l1 << 16));
        WR_SLOT(19, (unsigned)l2);
    }
    // coarse levels 0..5: f32 precision via hi/lo pair
#pragma unroll
    for (int l = 0; l < 6; ++l) {
        float f0, f1;
        gather_level(tbl4 + (size_t)l * TBL_SIZE, l < 4, lp.res[l], lp.scale[l],
                     px, py, pz, f0, f1);
        unsigned short h0, l0, h1, l1;
        split_bf16(f0, h0, l0);
        split_bf16(f1, h1, l1);
        WR_SLOT(2 + l, (unsigned)h0 | ((unsigned)h1 << 16));
        WR_SLOT(20 + l, (unsigned)l0 | ((unsigned)l1 << 16));
    }
    // fine levels 6..15 from paired feats
#pragma unroll
    for (int p = 0; p < 5; ++p) {
        u32x2 u = __builtin_nontemporal_load((const u32x2*)&featp[(size_t)p * n + ic]);
        WR_SLOT(8 + 2 * p, u.x);
        WR_SLOT(9 + 2 * p, u.y);
    }
#pragma unroll
    for (int s = 26; s < 32; ++s) WR_SLOT(s, 0u);
#undef WR_SLOT
    __syncthreads();

    // A fragments: row p = mt*16 + (lane&15), K-chunk = ks*32 + (lane>>4)*8
    bf16x8 a[4][2];
#pragma unroll
    for (int mt = 0; mt < 4; ++mt) {
        int p = mt * 16 + (lane & 15);
#pragma unroll
        for (int ks = 0; ks < 2; ++ks) {
            int off = p * 128 + ((ks * 64 + (lane >> 4) * 16) ^ ((p & 7) << 4));
            a[mt][ks] = *(const bf16x8*)(my + off);
        }
    }

    float part[4][4];
#pragma unroll
    for (int mt = 0; mt < 4; ++mt)
#pragma unroll
        for (int rr = 0; rr < 4; ++rr) part[mt][rr] = 0.f;

#pragma unroll
    for (int nt = 0; nt < 4; ++nt) {
        int col = nt * 16 + (lane & 15);
        int kb = (lane >> 4) * 8;
        bf16x8 bh0 = *(const bf16x8*)(Bh + col * 64 + kb);
        bf16x8 bh1 = *(const bf16x8*)(Bh + col * 64 + 32 + kb);
        bf16x8 bl0 = *(const bf16x8*)(Bl + col * 64 + kb);
        bf16x8 bl1 = *(const bf16x8*)(Bl + col * 64 + 32 + kb);
        float w2c = w[W2_OFF + col] * 0.01f;
#pragma unroll
        for (int mt = 0; mt < 4; ++mt) {
            f32x4 acc = {0.f, 0.f, 0.f, 0.f};
            acc = __builtin_amdgcn_mfma_f32_16x16x32_bf16(a[mt][0], bh0, acc, 0, 0, 0);
            acc = __builtin_amdgcn_mfma_f32_16x16x32_bf16(a[mt][1], bh1, acc, 0, 0, 0);
            acc = __builtin_amdgcn_mfma_f32_16x16x32_bf16(a[mt][0], bl0, acc, 0, 0, 0);
            acc = __builtin_amdgcn_mfma_f32_16x16x32_bf16(a[mt][1], bl1, acc, 0, 0, 0);
#pragma unroll
            for (int rr = 0; rr < 4; ++rr) {
                float t = 100.f * acc[rr];
                float e = __expf(-fabsf(t));
                float sp = fmaxf(t, 0.f) + __logf(1.f + e);
                part[mt][rr] = fmaf(w2c, sp, part[mt][rr]);
            }
        }
    }

    float b2v = w[B2_OFF];
#pragma unroll
    for (int mt = 0; mt < 4; ++mt) {
#pragma unroll
        for (int rr = 0; rr < 4; ++rr) {
            float v = part[mt][rr];
            v += __shfl_xor(v, 1);
            v += __shfl_xor(v, 2);
            v += __shfl_xor(v, 4);
            v += __shfl_xor(v, 8);
            if ((lane & 15) == mt) {
                int gi = base + mt * 16 + (lane >> 4) * 4 + rr;
                if (gi < n) out[sidx[gi]] = v + b2v;
            }
        }
    }
}

// fully fused fallback (tiny ws)
__global__ __launch_bounds__(256) void sdf_fused_kernel(
    const float* __restrict__ points, const float* __restrict__ table,
    const float* __restrict__ w, float* __restrict__ out, LP lp, int n) {
    int i = blockIdx.x * 256 + threadIdx.x;
    if (i >= n) return;
    float px = points[3 * i], py = points[3 * i + 1], pz = points[3 * i + 2];
    float f[35];
    f[0] = px * 2.f - 1.f; f[1] = py * 2.f - 1.f; f[2] = pz * 2.f - 1.f;
#pragma unroll
    for (int l = 0; l < NLV; ++l) {
        float scale = lp.scale[l];
        float fx = fmaf(px, scale, 0.5f), fy = fmaf(py, scale, 0.5f), fz = fmaf(pz, scale, 0.5f);
        float bx = floorf(fx), by = floorf(fy), bz = floorf(fz);
        float wx = fx - bx, wy = fy - by, wz = fz - bz;
        unsigned int ix = (unsigned int)bx, iy = (unsigned int)by, iz = (unsigned int)bz;
        const float* tl = table + (size_t)l * (TBL_SIZE * 2);
        float f0 = 0.f, f1 = 0.f;
#pragma unroll
        for (int c = 0; c < 8; ++c) {
            unsigned int qx = (c >> 2) & 1, qy = (c >> 1) & 1, qz = c & 1;
            unsigned int cx = ix + qx, cy = iy + qy, cz = iz + qz;
            unsigned int idx;
            if (l < 4) { unsigned int rr = lp.res[l]; idx = cx + cy * rr + cz * rr * rr; }
            else { idx = (cx * 1u) ^ (cy * 2654435761u) ^ (cz * 805459861u); idx &= TBL_MASK; }
            float cw = (qx ? wx : 1.f - wx) * (qy ? wy : 1.f - wy) * (qz ? wz : 1.f - wz);
            float2 g2v = *(const float2*)(tl + (size_t)idx * 2);
            f0 = fmaf(cw, g2v.x, f0); f1 = fmaf(cw, g2v.y, f1);
        }
        f[3 + 2 * l] = f0; f[4 + 2 * l] = f1;
    }
    float acc = w[B2_OFF];
#pragma unroll 4
    for (int j = 0; j < 64; ++j) {
        float hj = w[B1_OFF + j];
#pragma unroll
        for (int k = 0; k < 35; ++k) hj = fmaf(w[W1_OFF + j * 35 + k], f[k], hj);
        float t = 100.f * hj;
        float e = __expf(-fabsf(t));
        float sp = fmaxf(t, 0.f) + __logf(1.f + e);
        acc = fmaf(w[W2_OFF + j], sp * 0.01f, acc);
    }
    out[i] = acc;
}

extern "C" void kernel_launch(void* const* d_in, const int* in_sizes, int n_in,
                              void* d_out, int out_size, void* d_ws, size_t ws_size,
                              hipStream_t stream) {
    const float* points = (const float*)d_in[0];
    const float* table  = (const float*)d_in[1];
    const float* v1 = (const float*)d_in[2];
    const float* g1 = (const float*)d_in[3];
    const float* b1 = (const float*)d_in[4];
    const float* v2 = (const float*)d_in[5];
    const float* g2 = (const float*)d_in[6];
    const float* b2 = (const float*)d_in[7];
    float* out = (float*)d_out;
    float* w = (float*)d_ws;

    int n = in_sizes[0] / 3;

    LP lp;
    for (int l = 0; l < NLV; ++l) {
        double s = 32.0 * pow(1.3195079107728942, (double)l) - 1.0;
        lp.scale[l] = (float)s;
        lp.res[l] = (unsigned int)(ceil(s)) + 1u;
    }

    // ws layout (u32 slots): weights | tbl4[16T] | spts u2[n] | sidx[n] | hist | Bh | Bl | featp u2[5n]
    size_t off_tbl4 = WREG;
    size_t off_spts = off_tbl4 + (size_t)NLV * TBL_SIZE;
    size_t off_sidx = off_spts + (size_t)2 * n;
    size_t off_hist = off_sidx + (size_t)n;
    size_t off_bh   = off_hist + NBINS;          // 2048 u32 (64x64 bf16)
    size_t off_bl   = off_bh + 2048;
    size_t off_feat = off_bl + 2048;
    size_t need = (off_feat + (size_t)10 * n) * 4;

    int blocks = (n + 255) / 256;
    int hist_blocks = (NBINS + 255) / 256;
    if (ws_size >= need) {
        unsigned int* tbl4 = (unsigned int*)d_ws + off_tbl4;
        uint2* spts = (uint2*)((unsigned int*)d_ws + off_spts);
        unsigned int* sidx = (unsigned int*)d_ws + off_sidx;
        unsigned int* hist = (unsigned int*)d_ws + off_hist;
        unsigned short* Bh = (unsigned short*)((unsigned int*)d_ws + off_bh);
        unsigned short* Bl = (unsigned short*)((unsigned int*)d_ws + off_bl);
        uint2* featp = (uint2*)((unsigned int*)d_ws + off_feat);

        int total_pairs = NLV * TBL_SIZE / 2;
        int cvt_blocks = (total_pairs + 255) / 256;
        prep_kernel<<<1 + hist_blocks, 256, 0, stream>>>(v1, g1, b1, v2, g2, b2, w, hist, Bh, Bl);
        aux_kernel<<<cvt_blocks + blocks, 256, 0, stream>>>(table, tbl4, hist, points, n, cvt_blocks);
        scan_kernel<<<1, 1024, 0, stream>>>(hist);
        scatter_kernel<<<blocks, 256, 0, stream>>>(points, hist, spts, sidx, n);
        for (int p = 0; p < 5; ++p) {
            int l0 = 6 + 2 * p, l1 = 7 + 2 * p;
            hashP_kernel<<<blocks, 256, 0, stream>>>(
                spts, tbl4 + (size_t)l0 * TBL_SIZE, tbl4 + (size_t)l1 * TBL_SIZE,
                lp.scale[l0], lp.scale[l1], featp + (size_t)p * n, n);
        }
        mlp2_kernel<<<blocks, 256, 0, stream>>>(spts, sidx, tbl4, featp, w, Bh, Bl, out, lp, n);
    } else {
        prep_kernel<<<1, 256, 0, stream>>>(v1, g1, b1, v2, g2, b2, w, (unsigned int*)d_ws,
                                           (unsigned short*)d_ws, (unsigned short*)d_ws);
        sdf_fused_kernel<<<blocks, 256, 0, stream>>>(points, table, w, out, lp, n);
    }
}

// Round 14
// 944.342 us; speedup vs baseline: 1.0047x; 1.0047x over previous
//
#include <hip/hip_runtime.h>
#include <math.h>

#define NLV 16
#define TBL_SIZE (1u << 19)
#define TBL_MASK (TBL_SIZE - 1u)
#define NBINS 32768
#define QSCALE 2097152.0f   // 2^21
#define QINV   (1.0f / 2097152.0f)

// workspace float offsets (weights block, also used by fallback)
#define W1_OFF 0      // [64][35] row-major, weight-normed (f32)
#define B1_OFF 2240   // [64]
#define W2_OFF 2304   // [64]
#define B2_OFF 2368   // [1]
#define WREG   2432   // floats reserved (9728 B, 16B-aligned)

typedef __attribute__((ext_vector_type(4))) float f32x4;
typedef __attribute__((ext_vector_type(8))) short bf16x8;
typedef __attribute__((ext_vector_type(2))) unsigned int u32x2;
typedef __attribute__((ext_vector_type(4))) unsigned int u32x4;

struct LP {
    float scale[NLV];
    unsigned int res[NLV];
};

__device__ __forceinline__ unsigned int pack_bf16(float a, float b) {
    unsigned int ua = __float_as_uint(a);
    ua += 0x7fffu + ((ua >> 16) & 1u);           // RNE
    unsigned int ub = __float_as_uint(b);
    ub += 0x7fffu + ((ub >> 16) & 1u);
    return (ua >> 16) | (ub & 0xffff0000u);
}

__device__ __forceinline__ unsigned short bf16_rne(float x) {
    unsigned int u = __float_as_uint(x);
    u += 0x7fffu + ((u >> 16) & 1u);
    return (unsigned short)(u >> 16);
}

// x = hi + r exactly (hi = truncated-bf16 of x); lo = rne(r)
__device__ __forceinline__ void split_bf16(float x, unsigned short& hi, unsigned short& lo) {
    unsigned int u = __float_as_uint(x);
    hi = (unsigned short)(u >> 16);
    float r = x - __uint_as_float(u & 0xffff0000u);
    lo = bf16_rne(r);
}

// hi-pair word and lo-pair word for two floats
__device__ __forceinline__ void split_pair(float a, float b, unsigned int& hw, unsigned int& lw) {
    unsigned short ah, al, bh, bl;
    split_bf16(a, ah, al);
    split_bf16(b, bh, bl);
    hw = (unsigned)ah | ((unsigned)bh << 16);
    lw = (unsigned)al | ((unsigned)bl << 16);
}

__device__ __forceinline__ uint2 pack_pt(float px, float py, float pz) {
    unsigned int qx = (unsigned int)fminf(px * QSCALE, 2097151.0f);
    unsigned int qy = (unsigned int)fminf(py * QSCALE, 2097151.0f);
    unsigned int qz = (unsigned int)fminf(pz * QSCALE, 2097151.0f);
    uint2 r;
    r.x = qx | (qy << 21);
    r.y = (qy >> 11) | (qz << 10);
    return r;
}

__device__ __forceinline__ void unpack_pt(uint2 s, float& px, float& py, float& pz) {
    unsigned int qx = s.x & 0x1FFFFFu;
    unsigned int qy = (s.x >> 21) | ((s.y & 0x3FFu) << 11);
    unsigned int qz = (s.y >> 10) & 0x1FFFFFu;
    px = (float)qx * QINV;
    py = (float)qy * QINV;
    pz = (float)qz * QINV;
}

// merged x-pair trilinear gather for one level (dense or hashed)
__device__ __forceinline__ void gather_level(
    const unsigned int* __restrict__ tl, bool dense, unsigned int r, float scale,
    float px, float py, float pz, float& f0, float& f1) {
    float fx = fmaf(px, scale, 0.5f);
    float fy = fmaf(py, scale, 0.5f);
    float fz = fmaf(pz, scale, 0.5f);
    float bx = floorf(fx), by = floorf(fy), bz = floorf(fz);
    float wx = fx - bx, wy = fy - by, wz = fz - bz;
    unsigned int ix = (unsigned int)bx;
    unsigned int iy = (unsigned int)by;
    unsigned int iz = (unsigned int)bz;
    f0 = 0.f; f1 = 0.f;
    float omwx = 1.f - wx;
#pragma unroll
    for (int cyz = 0; cyz < 4; ++cyz) {
        unsigned int qy = cyz >> 1, qz = cyz & 1;
        unsigned int cy = iy + qy, cz = iz + qz;
        unsigned int i0, i1;
        if (dense) {
            i0 = ix + cy * r + cz * r * r;
            i1 = i0 + 1;
        } else {
            unsigned int ryz = (cy * 2654435761u) ^ (cz * 805459861u);
            i0 = (ix ^ ryz) & TBL_MASK;
            i1 = ((ix + 1u) ^ ryz) & TBL_MASK;
        }
        unsigned int sel = i0 & 1u;
        uint2 e = *(const uint2*)(tl + (i0 & ~1u));
        unsigned int lo_bits = sel ? e.y : e.x;
        unsigned int hi_bits = sel ? e.x : e.y;
        if (i1 != (i0 ^ 1u)) hi_bits = tl[i1];   // predicated: only unmerged lanes issue

        float wrow = (qy ? wy : 1.f - wy) * (qz ? wz : 1.f - wz);
        float wlo = wrow * omwx, whi = wrow * wx;
        f0 = fmaf(wlo, __uint_as_float(lo_bits << 16), f0);
        f1 = fmaf(wlo, __uint_as_float(lo_bits & 0xffff0000u), f1);
        f0 = fmaf(whi, __uint_as_float(hi_bits << 16), f0);
        f1 = fmaf(whi, __uint_as_float(hi_bits & 0xffff0000u), f1);
    }
}

// block 0: weight-norm prep + MFMA B-matrix build; blocks 1..: zero hist
// K-order (u32 slot s <-> K=2s,2s+1):
//  slot0: c0,c1  slot1: c2,BIAS(=1)  slot2+l (l=0..15): Lf0,Lf1
//  slot18: c0lo,c1lo  slot19: c2lo,0  slot20+l (l=0..5): Lf0lo,Lf1lo  slots26..31: 0
__global__ __launch_bounds__(256) void prep_kernel(
    const float* __restrict__ v1, const float* __restrict__ g1,
    const float* __restrict__ b1, const float* __restrict__ v2,
    const float* __restrict__ g2, const float* __restrict__ b2,
    float* __restrict__ w, unsigned int* __restrict__ hist,
    unsigned short* __restrict__ Bh, unsigned short* __restrict__ Bl) {
    int bid = blockIdx.x;
    if (bid > 0) {
        int t = (bid - 1) * 256 + threadIdx.x;
        if (t < NBINS) hist[t] = 0;
        return;
    }
    if (threadIdx.x >= 64) return;
    int j = threadIdx.x;
    float wn[35];
    float s = 0.f;
#pragma unroll
    for (int k = 0; k < 35; ++k) { float x = v1[j * 35 + k]; s += x * x; }
    float sc = g1[j] / sqrtf(s);
#pragma unroll
    for (int k = 0; k < 35; ++k) {
        wn[k] = v1[j * 35 + k] * sc;
        w[W1_OFF + j * 35 + k] = wn[k];
    }
    float b1j = b1[j];
    w[B1_OFF + j] = b1j;
    float s2 = 0.f;
#pragma unroll
    for (int i2 = 0; i2 < 64; ++i2) { float x = v2[i2]; s2 += x * x; }
    w[W2_OFF + j] = v2[j] * (g2[0] / sqrtf(s2));
    if (j == 0) w[B2_OFF] = b2[0];

#pragma unroll
    for (int k = 0; k < 64; ++k) {
        float v = 0.f;
        if (k < 3) v = wn[k];
        else if (k == 3) v = b1j;
        else if (k < 36) v = wn[k - 1];
        else if (k < 39) v = wn[k - 36];
        else if (k == 39) v = 0.f;
        else if (k < 52) v = wn[k - 37];
        unsigned short hi, lo;
        split_bf16(v, hi, lo);
        Bh[j * 64 + k] = hi;
        Bl[j * 64 + k] = lo;
    }
}

__device__ __forceinline__ unsigned int bin_key(float px, float py, float pz) {
    unsigned int ix = (unsigned int)floorf(fmaf(px, 31.f, 0.5f));
    unsigned int iy = (unsigned int)floorf(fmaf(py, 31.f, 0.5f));
    unsigned int iz = (unsigned int)floorf(fmaf(pz, 31.f, 0.5f));
    ix = min(ix, 31u); iy = min(iy, 31u); iz = min(iz, 31u);
    return ix | (iy << 5) | (iz << 10);
}

// fused: table convert | bin count (disjoint outputs)
__global__ __launch_bounds__(256) void aux_kernel(
    const float* __restrict__ table, unsigned int* __restrict__ tbl4,
    unsigned int* __restrict__ hist, const float* __restrict__ points,
    int n, int cvt_blocks) {
    int bid = blockIdx.x;
    if (bid < cvt_blocks) {
        int t = bid * 256 + threadIdx.x;
        int total_pairs = NLV * TBL_SIZE / 2;
        if (t >= total_pairs) return;
        const float4 v = *(const float4*)(table + (size_t)t * 4);
        uint2 o;
        o.x = pack_bf16(v.x, v.y);
        o.y = pack_bf16(v.z, v.w);
        *(uint2*)(tbl4 + (size_t)t * 2) = o;
    } else {
        int i = (bid - cvt_blocks) * 256 + threadIdx.x;
        if (i >= n) return;
        unsigned int k = bin_key(points[3 * i], points[3 * i + 1], points[3 * i + 2]);
        atomicAdd(&hist[k], 1u);
    }
}

// single-block exclusive scan of 32768 bins
__global__ __launch_bounds__(1024) void scan_kernel(unsigned int* __restrict__ hist) {
    __shared__ unsigned int part[1024];
    int tid = threadIdx.x;
    int base = tid * 32;
    unsigned int s = 0;
#pragma unroll
    for (int k = 0; k < 32; ++k) s += hist[base + k];
    part[tid] = s;
    __syncthreads();
    for (int d = 1; d < 1024; d <<= 1) {
        unsigned int v = (tid >= d) ? part[tid - d] : 0u;
        __syncthreads();
        part[tid] += v;
        __syncthreads();
    }
    unsigned int run = part[tid] - s;
#pragma unroll
    for (int k = 0; k < 32; ++k) {
        unsigned int t = hist[base + k];
        hist[base + k] = run;
        run += t;
    }
}

__global__ __launch_bounds__(256) void scatter_kernel(const float* __restrict__ points,
                                                      unsigned int* __restrict__ hist,
                                                      uint2* __restrict__ spts,
                                                      unsigned int* __restrict__ sidx, int n) {
    int i = blockIdx.x * 256 + threadIdx.x;
    if (i >= n) return;
    float px = points[3 * i], py = points[3 * i + 1], pz = points[3 * i + 2];
    unsigned int k = bin_key(px, py, pz);
    unsigned int pos = atomicAdd(&hist[k], 1u);
    spts[pos] = pack_pt(px, py, pz);
    sidx[pos] = (unsigned int)i;
}

// 3 coarse pairs (levels 0..5) in one dispatch (line-shared, L1-friendly);
// hi+lo stored as uint4 to preserve f32 precision in the MLP
__global__ __launch_bounds__(256) void hashC_kernel(
    const uint2* __restrict__ spts, const unsigned int* __restrict__ tbl4,
    u32x4* __restrict__ featc, LP lp, int n, int bpl) {
    int bid = blockIdx.x;
    int pp = bid / bpl;                 // 0..2 -> levels (2pp, 2pp+1)
    int i = (bid - pp * bpl) * 256 + threadIdx.x;
    if (i >= n) return;
    float px, py, pz;
    unpack_pt(spts[i], px, py, pz);
    int l0 = 2 * pp, l1 = 2 * pp + 1;
    float a0, a1, b0, b1;
    gather_level(tbl4 + (size_t)l0 * TBL_SIZE, l0 < 4, lp.res[l0], lp.scale[l0], px, py, pz, a0, a1);
    gather_level(tbl4 + (size_t)l1 * TBL_SIZE, l1 < 4, lp.res[l1], lp.scale[l1], px, py, pz, b0, b1);
    unsigned int hx, lx, hy, ly;
    split_pair(a0, a1, hx, lx);
    split_pair(b0, b1, hy, ly);
    u32x4 o;
    o.x = hx; o.y = hy; o.z = lx; o.w = ly;
    __builtin_nontemporal_store(o, &featc[(size_t)pp * n + i]);
}

// one PAIR of fine hash levels per dispatch (4MB slab = one XCD L2)
__global__ __launch_bounds__(256) void hashP_kernel(
    const uint2* __restrict__ spts, const unsigned int* __restrict__ tl0,
    const unsigned int* __restrict__ tl1, float scale0, float scale1,
    u32x2* __restrict__ featp, int n) {
    int i = blockIdx.x * 256 + threadIdx.x;
    if (i >= n) return;
    float px, py, pz;
    unpack_pt(spts[i], px, py, pz);
    float a0, a1, b0, b1;
    gather_level(tl0, false, 0u, scale0, px, py, pz, a0, a1);
    gather_level(tl1, false, 0u, scale1, px, py, pz, b0, b1);
    u32x2 o;
    o.x = pack_bf16(a0, a1);
    o.y = pack_bf16(b0, b1);
    __builtin_nontemporal_store(o, &featp[i]);
}

// pure MLP: feats -> LDS (swizzled) -> MFMA (hi/lo) -> softplus -> butterfly -> store
__global__ __launch_bounds__(256) void mlp3_kernel(
    const uint2* __restrict__ spts, const unsigned int* __restrict__ sidx,
    const u32x4* __restrict__ featc, const u32x2* __restrict__ featp,
    const float* __restrict__ w, const unsigned short* __restrict__ Bh,
    const unsigned short* __restrict__ Bl, float* __restrict__ out, int n) {
    __shared__ unsigned int lds[4][64][32];     // 8KB per wave (private per wave)
    int lane = threadIdx.x & 63;
    int wid = threadIdx.x >> 6;
    int base = blockIdx.x * 256 + wid * 64;
    if (base >= n) return;
    int i = base + lane;
    int ic = (i < n) ? i : (n - 1);

    float px, py, pz;
    unpack_pt(spts[ic], px, py, pz);

    char* my = (char*)&lds[wid][0][0];
    int rowoff = lane * 128;
    int swz = (lane & 7) << 4;
#define WR_SLOT(s, v) *(unsigned int*)(my + rowoff + (((s) * 4) ^ swz)) = (v)

    {
        unsigned int h01, l01;
        split_pair(px * 2.f - 1.f, py * 2.f - 1.f, h01, l01);
        unsigned short h2, l2;
        split_bf16(pz * 2.f - 1.f, h2, l2);
        WR_SLOT(0, h01);
        WR_SLOT(1, (unsigned)h2 | (0x3f80u << 16));      // bias slot = 1.0
        WR_SLOT(18, l01);
        WR_SLOT(19, (unsigned)l2);
    }
    // coarse pairs: hi -> slots 2..7, lo -> slots 20..25
#pragma unroll
    for (int p = 0; p < 3; ++p) {
        u32x4 u = __builtin_nontemporal_load(&featc[(size_t)p * n + ic]);
        WR_SLOT(2 + 2 * p, u.x);
        WR_SLOT(3 + 2 * p, u.y);
        WR_SLOT(20 + 2 * p, u.z);
        WR_SLOT(21 + 2 * p, u.w);
    }
    // fine pairs: slots 8..17
#pragma unroll
    for (int p = 0; p < 5; ++p) {
        u32x2 u = __builtin_nontemporal_load(&featp[(size_t)p * n + ic]);
        WR_SLOT(8 + 2 * p, u.x);
        WR_SLOT(9 + 2 * p, u.y);
    }
#pragma unroll
    for (int s = 26; s < 32; ++s) WR_SLOT(s, 0u);
#undef WR_SLOT
    __syncthreads();

    // A fragments: row p = mt*16 + (lane&15), K-chunk = ks*32 + (lane>>4)*8
    bf16x8 a[4][2];
#pragma unroll
    for (int mt = 0; mt < 4; ++mt) {
        int p = mt * 16 + (lane & 15);
#pragma unroll
        for (int ks = 0; ks < 2; ++ks) {
            int off = p * 128 + ((ks * 64 + (lane >> 4) * 16) ^ ((p & 7) << 4));
            a[mt][ks] = *(const bf16x8*)(my + off);
        }
    }

    float part[4][4];
#pragma unroll
    for (int mt = 0; mt < 4; ++mt)
#pragma unroll
        for (int rr = 0; rr < 4; ++rr) part[mt][rr] = 0.f;

#pragma unroll
    for (int nt = 0; nt < 4; ++nt) {
        int col = nt * 16 + (lane & 15);
        int kb = (lane >> 4) * 8;
        bf16x8 bh0 = *(const bf16x8*)(Bh + col * 64 + kb);
        bf16x8 bh1 = *(const bf16x8*)(Bh + col * 64 + 32 + kb);
        bf16x8 bl0 = *(const bf16x8*)(Bl + col * 64 + kb);
        bf16x8 bl1 = *(const bf16x8*)(Bl + col * 64 + 32 + kb);
        float w2c = w[W2_OFF + col] * 0.01f;
#pragma unroll
        for (int mt = 0; mt < 4; ++mt) {
            f32x4 acc = {0.f, 0.f, 0.f, 0.f};
            acc = __builtin_amdgcn_mfma_f32_16x16x32_bf16(a[mt][0], bh0, acc, 0, 0, 0);
            acc = __builtin_amdgcn_mfma_f32_16x16x32_bf16(a[mt][1], bh1, acc, 0, 0, 0);
            acc = __builtin_amdgcn_mfma_f32_16x16x32_bf16(a[mt][0], bl0, acc, 0, 0, 0);
            acc = __builtin_amdgcn_mfma_f32_16x16x32_bf16(a[mt][1], bl1, acc, 0, 0, 0);
#pragma unroll
            for (int rr = 0; rr < 4; ++rr) {
                float t = 100.f * acc[rr];
                float e = __expf(-fabsf(t));
                float sp = fmaxf(t, 0.f) + __logf(1.f + e);
                part[mt][rr] = fmaf(w2c, sp, part[mt][rr]);
            }
        }
    }

    float b2v = w[B2_OFF];
#pragma unroll
    for (int mt = 0; mt < 4; ++mt) {
#pragma unroll
        for (int rr = 0; rr < 4; ++rr) {
            float v = part[mt][rr];
            v += __shfl_xor(v, 1);
            v += __shfl_xor(v, 2);
            v += __shfl_xor(v, 4);
            v += __shfl_xor(v, 8);
            if ((lane & 15) == mt) {
                int gi = base + mt * 16 + (lane >> 4) * 4 + rr;
                if (gi < n) out[sidx[gi]] = v + b2v;
            }
        }
    }
}

// fully fused fallback (tiny ws)
__global__ __launch_bounds__(256) void sdf_fused_kernel(
    const float* __restrict__ points, const float* __restrict__ table,
    const float* __restrict__ w, float* __restrict__ out, LP lp, int n) {
    int i = blockIdx.x * 256 + threadIdx.x;
    if (i >= n) return;
    float px = points[3 * i], py = points[3 * i + 1], pz = points[3 * i + 2];
    float f[35];
    f[0] = px * 2.f - 1.f; f[1] = py * 2.f - 1.f; f[2] = pz * 2.f - 1.f;
#pragma unroll
    for (int l = 0; l < NLV; ++l) {
        float scale = lp.scale[l];
        float fx = fmaf(px, scale, 0.5f), fy = fmaf(py, scale, 0.5f), fz = fmaf(pz, scale, 0.5f);
        float bx = floorf(fx), by = floorf(fy), bz = floorf(fz);
        float wx = fx - bx, wy = fy - by, wz = fz - bz;
        unsigned int ix = (unsigned int)bx, iy = (unsigned int)by, iz = (unsigned int)bz;
        const float* tl = table + (size_t)l * (TBL_SIZE * 2);
        float f0 = 0.f, f1 = 0.f;
#pragma unroll
        for (int c = 0; c < 8; ++c) {
            unsigned int qx = (c >> 2) & 1, qy = (c >> 1) & 1, qz = c & 1;
            unsigned int cx = ix + qx, cy = iy + qy, cz = iz + qz;
            unsigned int idx;
            if (l < 4) { unsigned int rr = lp.res[l]; idx = cx + cy * rr + cz * rr * rr; }
            else { idx = (cx * 1u) ^ (cy * 2654435761u) ^ (cz * 805459861u); idx &= TBL_MASK; }
            float cw = (qx ? wx : 1.f - wx) * (qy ? wy : 1.f - wy) * (qz ? wz : 1.f - wz);
            float2 g2v = *(const float2*)(tl + (size_t)idx * 2);
            f0 = fmaf(cw, g2v.x, f0); f1 = fmaf(cw, g2v.y, f1);
        }
        f[3 + 2 * l] = f0; f[4 + 2 * l] = f1;
    }
    float acc = w[B2_OFF];
#pragma unroll 4
    for (int j = 0; j < 64; ++j) {
        float hj = w[B1_OFF + j];
#pragma unroll
        for (int k = 0; k < 35; ++k) hj = fmaf(w[W1_OFF + j * 35 + k], f[k], hj);
        float t = 100.f * hj;
        float e = __expf(-fabsf(t));
        float sp = fmaxf(t, 0.f) + __logf(1.f + e);
        acc = fmaf(w[W2_OFF + j], sp * 0.01f, acc);
    }
    out[i] = acc;
}

extern "C" void kernel_launch(void* const* d_in, const int* in_sizes, int n_in,
                              void* d_out, int out_size, void* d_ws, size_t ws_size,
                              hipStream_t stream) {
    const float* points = (const float*)d_in[0];
    const float* table  = (const float*)d_in[1];
    const float* v1 = (const float*)d_in[2];
    const float* g1 = (const float*)d_in[3];
    const float* b1 = (const float*)d_in[4];
    const float* v2 = (const float*)d_in[5];
    const float* g2 = (const float*)d_in[6];
    const float* b2 = (const float*)d_in[7];
    float* out = (float*)d_out;
    float* w = (float*)d_ws;

    int n = in_sizes[0] / 3;

    LP lp;
    for (int l = 0; l < NLV; ++l) {
        double s = 32.0 * pow(1.3195079107728942, (double)l) - 1.0;
        lp.scale[l] = (float)s;
        lp.res[l] = (unsigned int)(ceil(s)) + 1u;
    }

    // ws (u32 slots): weights | tbl4[16T] | spts u2[n] | sidx[n] | hist | Bh | Bl | featc u4[3n] | featp u2[5n]
    size_t off_tbl4 = WREG;
    size_t off_spts = off_tbl4 + (size_t)NLV * TBL_SIZE;
    size_t off_sidx = off_spts + (size_t)2 * n;
    size_t off_hist = off_sidx + (size_t)n;
    size_t off_bh   = off_hist + NBINS;          // 2048 u32 (64x64 bf16)
    size_t off_bl   = off_bh + 2048;
    size_t off_fc   = off_bl + 2048;
    size_t off_fp   = off_fc + (size_t)12 * n;
    size_t need = (off_fp + (size_t)10 * n) * 4;

    int blocks = (n + 255) / 256;
    int hist_blocks = (NBINS + 255) / 256;
    if (ws_size >= need) {
        unsigned int* tbl4 = (unsigned int*)d_ws + off_tbl4;
        uint2* spts = (uint2*)((unsigned int*)d_ws + off_spts);
        unsigned int* sidx = (unsigned int*)d_ws + off_sidx;
        unsigned int* hist = (unsigned int*)d_ws + off_hist;
        unsigned short* Bh = (unsigned short*)((unsigned int*)d_ws + off_bh);
        unsigned short* Bl = (unsigned short*)((unsigned int*)d_ws + off_bl);
        u32x4* featc = (u32x4*)((unsigned int*)d_ws + off_fc);
        u32x2* featp = (u32x2*)((unsigned int*)d_ws + off_fp);

        int total_pairs = NLV * TBL_SIZE / 2;
        int cvt_blocks = (total_pairs + 255) / 256;
        prep_kernel<<<1 + hist_blocks, 256, 0, stream>>>(v1, g1, b1, v2, g2, b2, w, hist, Bh, Bl);
        aux_kernel<<<cvt_blocks + blocks, 256, 0, stream>>>(table, tbl4, hist, points, n, cvt_blocks);
        scan_kernel<<<1, 1024, 0, stream>>>(hist);
        scatter_kernel<<<blocks, 256, 0, stream>>>(points, hist, spts, sidx, n);
        hashC_kernel<<<3 * blocks, 256, 0, stream>>>(spts, tbl4, featc, lp, n, blocks);
        for (int p = 0; p < 5; ++p) {
            int l0 = 6 + 2 * p, l1 = 7 + 2 * p;
            hashP_kernel<<<blocks, 256, 0, stream>>>(
                spts, tbl4 + (size_t)l0 * TBL_SIZE, tbl4 + (size_t)l1 * TBL_SIZE,
                lp.scale[l0], lp.scale[l1], featp + (size_t)p * n, n);
        }
        mlp3_kernel<<<blocks, 256, 0, stream>>>(spts, sidx, featc, featp, w, Bh, Bl, out, n);
    } else {
        prep_kernel<<<1, 256, 0, stream>>>(v1, g1, b1, v2, g2, b2, w, (unsigned int*)d_ws,
                                           (unsigned short*)d_ws, (unsigned short*)d_ws);
        sdf_fused_kernel<<<blocks, 256, 0, stream>>>(points, table, w, out, lp, n);
    }
}

// Round 15
// 922.666 us; speedup vs baseline: 1.0283x; 1.0235x over previous
//
#include <hip/hip_runtime.h>
#include <math.h>

#define NLV 16
#define NFINE 10
#define TBL_SIZE (1u << 19)
#define TBL_MASK (TBL_SIZE - 1u)
#define NBINS 32768
#define QSCALE 2097152.0f   // 2^21
#define QINV   (1.0f / 2097152.0f)

// workspace float offsets (weights block, also used by fallback)
#define W1_OFF 0      // [64][35] row-major, weight-normed (f32)
#define B1_OFF 2240   // [64]
#define W2_OFF 2304   // [64]
#define B2_OFF 2368   // [1]
#define WREG   2432   // floats reserved (9728 B, 16B-aligned)

typedef __attribute__((ext_vector_type(4))) float f32x4;
typedef __attribute__((ext_vector_type(8))) short bf16x8;
typedef __attribute__((ext_vector_type(2))) unsigned int u32x2;
typedef __attribute__((ext_vector_type(4))) unsigned int u32x4;

struct LP {
    float scale[NLV];
    unsigned int res[NLV];
};

__device__ __forceinline__ unsigned int pack_bf16(float a, float b) {
    unsigned int ua = __float_as_uint(a);
    ua += 0x7fffu + ((ua >> 16) & 1u);           // RNE
    unsigned int ub = __float_as_uint(b);
    ub += 0x7fffu + ((ub >> 16) & 1u);
    return (ua >> 16) | (ub & 0xffff0000u);
}

__device__ __forceinline__ unsigned short bf16_rne(float x) {
    unsigned int u = __float_as_uint(x);
    u += 0x7fffu + ((u >> 16) & 1u);
    return (unsigned short)(u >> 16);
}

// x = hi + r exactly (hi = truncated-bf16 of x); lo = rne(r)
__device__ __forceinline__ void split_bf16(float x, unsigned short& hi, unsigned short& lo) {
    unsigned int u = __float_as_uint(x);
    hi = (unsigned short)(u >> 16);
    float r = x - __uint_as_float(u & 0xffff0000u);
    lo = bf16_rne(r);
}

// hi-pair word and lo-pair word for two floats
__device__ __forceinline__ void split_pair(float a, float b, unsigned int& hw, unsigned int& lw) {
    unsigned short ah, al, bh, bl;
    split_bf16(a, ah, al);
    split_bf16(b, bh, bl);
    hw = (unsigned)ah | ((unsigned)bh << 16);
    lw = (unsigned)al | ((unsigned)bl << 16);
}

__device__ __forceinline__ uint2 pack_pt(float px, float py, float pz) {
    unsigned int qx = (unsigned int)fminf(px * QSCALE, 2097151.0f);
    unsigned int qy = (unsigned int)fminf(py * QSCALE, 2097151.0f);
    unsigned int qz = (unsigned int)fminf(pz * QSCALE, 2097151.0f);
    uint2 r;
    r.x = qx | (qy << 21);
    r.y = (qy >> 11) | (qz << 10);
    return r;
}

__device__ __forceinline__ void unpack_pt2(unsigned int sx, unsigned int sy,
                                           float& px, float& py, float& pz) {
    unsigned int qx = sx & 0x1FFFFFu;
    unsigned int qy = (sx >> 21) | ((sy & 0x3FFu) << 11);
    unsigned int qz = (sy >> 10) & 0x1FFFFFu;
    px = (float)qx * QINV;
    py = (float)qy * QINV;
    pz = (float)qz * QINV;
}

// merged x-pair trilinear gather for one level (dense or hashed)
__device__ __forceinline__ void gather_level(
    const unsigned int* __restrict__ tl, bool dense, unsigned int r, float scale,
    float px, float py, float pz, float& f0, float& f1) {
    float fx = fmaf(px, scale, 0.5f);
    float fy = fmaf(py, scale, 0.5f);
    float fz = fmaf(pz, scale, 0.5f);
    float bx = floorf(fx), by = floorf(fy), bz = floorf(fz);
    float wx = fx - bx, wy = fy - by, wz = fz - bz;
    unsigned int ix = (unsigned int)bx;
    unsigned int iy = (unsigned int)by;
    unsigned int iz = (unsigned int)bz;
    f0 = 0.f; f1 = 0.f;
    float omwx = 1.f - wx;
#pragma unroll
    for (int cyz = 0; cyz < 4; ++cyz) {
        unsigned int qy = cyz >> 1, qz = cyz & 1;
        unsigned int cy = iy + qy, cz = iz + qz;
        unsigned int i0, i1;
        if (dense) {
            i0 = ix + cy * r + cz * r * r;
            i1 = i0 + 1;
        } else {
            unsigned int ryz = (cy * 2654435761u) ^ (cz * 805459861u);
            i0 = (ix ^ ryz) & TBL_MASK;
            i1 = ((ix + 1u) ^ ryz) & TBL_MASK;
        }
        unsigned int sel = i0 & 1u;
        uint2 e = *(const uint2*)(tl + (i0 & ~1u));
        unsigned int lo_bits = sel ? e.y : e.x;
        unsigned int hi_bits = sel ? e.x : e.y;
        if (i1 != (i0 ^ 1u)) hi_bits = tl[i1];   // predicated: only unmerged lanes issue

        float wrow = (qy ? wy : 1.f - wy) * (qz ? wz : 1.f - wz);
        float wlo = wrow * omwx, whi = wrow * wx;
        f0 = fmaf(wlo, __uint_as_float(lo_bits << 16), f0);
        f1 = fmaf(wlo, __uint_as_float(lo_bits & 0xffff0000u), f1);
        f0 = fmaf(whi, __uint_as_float(hi_bits << 16), f0);
        f1 = fmaf(whi, __uint_as_float(hi_bits & 0xffff0000u), f1);
    }
}

// block 0: weight-norm prep + MFMA B-matrix build; blocks 1..: zero hist
// K-order (u32 slot s <-> K=2s,2s+1):
//  slot0: c0,c1  slot1: c2,BIAS(=1)  slot2+l (l=0..15): Lf0,Lf1
//  slot18: c0lo,c1lo  slot19: c2lo,0  slot20+l (l=0..5): Lf0lo,Lf1lo  slots26..31: 0
__global__ __launch_bounds__(256) void prep_kernel(
    const float* __restrict__ v1, const float* __restrict__ g1,
    const float* __restrict__ b1, const float* __restrict__ v2,
    const float* __restrict__ g2, const float* __restrict__ b2,
    float* __restrict__ w, unsigned int* __restrict__ hist,
    unsigned short* __restrict__ Bh, unsigned short* __restrict__ Bl) {
    int bid = blockIdx.x;
    if (bid > 0) {
        int t = (bid - 1) * 256 + threadIdx.x;
        if (t < NBINS) hist[t] = 0;
        return;
    }
    if (threadIdx.x >= 64) return;
    int j = threadIdx.x;
    float wn[35];
    float s = 0.f;
#pragma unroll
    for (int k = 0; k < 35; ++k) { float x = v1[j * 35 + k]; s += x * x; }
    float sc = g1[j] / sqrtf(s);
#pragma unroll
    for (int k = 0; k < 35; ++k) {
        wn[k] = v1[j * 35 + k] * sc;
        w[W1_OFF + j * 35 + k] = wn[k];
    }
    float b1j = b1[j];
    w[B1_OFF + j] = b1j;
    float s2 = 0.f;
#pragma unroll
    for (int i2 = 0; i2 < 64; ++i2) { float x = v2[i2]; s2 += x * x; }
    w[W2_OFF + j] = v2[j] * (g2[0] / sqrtf(s2));
    if (j == 0) w[B2_OFF] = b2[0];

#pragma unroll
    for (int k = 0; k < 64; ++k) {
        float v = 0.f;
        if (k < 3) v = wn[k];
        else if (k == 3) v = b1j;
        else if (k < 36) v = wn[k - 1];
        else if (k < 39) v = wn[k - 36];
        else if (k == 39) v = 0.f;
        else if (k < 52) v = wn[k - 37];
        unsigned short hi, lo;
        split_bf16(v, hi, lo);
        Bh[j * 64 + k] = hi;
        Bl[j * 64 + k] = lo;
    }
}

__device__ __forceinline__ unsigned int bin_key(float px, float py, float pz) {
    unsigned int ix = (unsigned int)floorf(fmaf(px, 31.f, 0.5f));
    unsigned int iy = (unsigned int)floorf(fmaf(py, 31.f, 0.5f));
    unsigned int iz = (unsigned int)floorf(fmaf(pz, 31.f, 0.5f));
    ix = min(ix, 31u); iy = min(iy, 31u); iz = min(iz, 31u);
    return ix | (iy << 5) | (iz << 10);
}

// fused: table convert | bin count (disjoint outputs)
__global__ __launch_bounds__(256) void aux_kernel(
    const float* __restrict__ table, unsigned int* __restrict__ tbl4,
    unsigned int* __restrict__ hist, const float* __restrict__ points,
    int n, int cvt_blocks) {
    int bid = blockIdx.x;
    if (bid < cvt_blocks) {
        int t = bid * 256 + threadIdx.x;
        int total_pairs = NLV * TBL_SIZE / 2;
        if (t >= total_pairs) return;
        const float4 v = *(const float4*)(table + (size_t)t * 4);
        uint2 o;
        o.x = pack_bf16(v.x, v.y);
        o.y = pack_bf16(v.z, v.w);
        *(uint2*)(tbl4 + (size_t)t * 2) = o;
    } else {
        int i = (bid - cvt_blocks) * 256 + threadIdx.x;
        if (i >= n) return;
        unsigned int k = bin_key(points[3 * i], points[3 * i + 1], points[3 * i + 2]);
        atomicAdd(&hist[k], 1u);
    }
}

// single-block exclusive scan of 32768 bins
__global__ __launch_bounds__(1024) void scan_kernel(unsigned int* __restrict__ hist) {
    __shared__ unsigned int part[1024];
    int tid = threadIdx.x;
    int base = tid * 32;
    unsigned int s = 0;
#pragma unroll
    for (int k = 0; k < 32; ++k) s += hist[base + k];
    part[tid] = s;
    __syncthreads();
    for (int d = 1; d < 1024; d <<= 1) {
        unsigned int v = (tid >= d) ? part[tid - d] : 0u;
        __syncthreads();
        part[tid] += v;
        __syncthreads();
    }
    unsigned int run = part[tid] - s;
#pragma unroll
    for (int k = 0; k < 32; ++k) {
        unsigned int t = hist[base + k];
        hist[base + k] = run;
        run += t;
    }
}

__global__ __launch_bounds__(256) void scatter_kernel(const float* __restrict__ points,
                                                      unsigned int* __restrict__ hist,
                                                      uint2* __restrict__ spts,
                                                      unsigned int* __restrict__ sidx, int n) {
    int i = blockIdx.x * 256 + threadIdx.x;
    if (i >= n) return;
    float px = points[3 * i], py = points[3 * i + 1], pz = points[3 * i + 2];
    unsigned int k = bin_key(px, py, pz);
    unsigned int pos = atomicAdd(&hist[k], 1u);
    spts[pos] = pack_pt(px, py, pz);
    sidx[pos] = (unsigned int)i;
}

// 3 coarse pairs (levels 0..5) in one dispatch (line-shared, L1-friendly);
// hi+lo stored as uint4 to preserve f32 precision in the MLP
__global__ __launch_bounds__(256) void hashC_kernel(
    const uint2* __restrict__ spts, const unsigned int* __restrict__ tbl4,
    u32x4* __restrict__ featc, LP lp, int n, int bpl) {
    int bid = blockIdx.x;
    int pp = bid / bpl;                 // 0..2 -> levels (2pp, 2pp+1)
    int i = (bid - pp * bpl) * 256 + threadIdx.x;
    if (i >= n) return;
    uint2 sp = spts[i];
    float px, py, pz;
    unpack_pt2(sp.x, sp.y, px, py, pz);
    int l0 = 2 * pp, l1 = 2 * pp + 1;
    float a0, a1, b0, b1;
    gather_level(tbl4 + (size_t)l0 * TBL_SIZE, l0 < 4, lp.res[l0], lp.scale[l0], px, py, pz, a0, a1);
    gather_level(tbl4 + (size_t)l1 * TBL_SIZE, l1 < 4, lp.res[l1], lp.scale[l1], px, py, pz, b0, b1);
    unsigned int hx, lx, hy, ly;
    split_pair(a0, a1, hx, lx);
    split_pair(b0, b1, hy, ly);
    u32x4 o;
    o.x = hx; o.y = hy; o.z = lx; o.w = ly;
    __builtin_nontemporal_store(o, &featc[(size_t)pp * n + i]);
}

// fine levels 6..15: ONE dispatch, single-level slices (2MB slab L2-resident),
// TWO points per thread to double outstanding gather requests (MLP/latency fix)
__global__ __launch_bounds__(256) void hashS_kernel(
    const unsigned int* __restrict__ spts_u32, const unsigned int* __restrict__ tbl4,
    unsigned int* __restrict__ feat, LP lp, int n, int bpl) {
    int bid = blockIdx.x;
    int lv = bid / bpl;                 // 0..9
    int level = lv + 6;
    int i = ((bid - lv * bpl) * 256 + threadIdx.x) * 2;
    if (i >= n) return;

    u32x4 pp = *(const u32x4*)(spts_u32 + (size_t)2 * i);   // 2 packed points (16B)
    float px0, py0, pz0, px1, py1, pz1;
    unpack_pt2(pp.x, pp.y, px0, py0, pz0);
    unpack_pt2(pp.z, pp.w, px1, py1, pz1);

    const unsigned int* tl = tbl4 + (size_t)level * TBL_SIZE;
    float scale = lp.scale[level];
    float a0, a1, b0, b1;
    gather_level(tl, false, 0u, scale, px0, py0, pz0, a0, a1);
    gather_level(tl, false, 0u, scale, px1, py1, pz1, b0, b1);

    if (i + 1 < n) {
        u32x2 o;
        o.x = pack_bf16(a0, a1);
        o.y = pack_bf16(b0, b1);
        __builtin_nontemporal_store(o, (u32x2*)&feat[(size_t)lv * n + i]);
    } else {
        feat[(size_t)lv * n + i] = pack_bf16(a0, a1);
    }
}

// pure MLP: feats -> LDS (swizzled) -> MFMA (hi/lo) -> softplus -> butterfly -> store
__global__ __launch_bounds__(256) void mlp3_kernel(
    const uint2* __restrict__ spts, const unsigned int* __restrict__ sidx,
    const u32x4* __restrict__ featc, const unsigned int* __restrict__ feat,
    const float* __restrict__ w, const unsigned short* __restrict__ Bh,
    const unsigned short* __restrict__ Bl, float* __restrict__ out, int n) {
    __shared__ unsigned int lds[4][64][32];     // 8KB per wave (private per wave)
    int lane = threadIdx.x & 63;
    int wid = threadIdx.x >> 6;
    int base = blockIdx.x * 256 + wid * 64;
    if (base >= n) return;
    int i = base + lane;
    int ic = (i < n) ? i : (n - 1);

    uint2 sp = spts[ic];
    float px, py, pz;
    unpack_pt2(sp.x, sp.y, px, py, pz);

    char* my = (char*)&lds[wid][0][0];
    int rowoff = lane * 128;
    int swz = (lane & 7) << 4;
#define WR_SLOT(s, v) *(unsigned int*)(my + rowoff + (((s) * 4) ^ swz)) = (v)

    {
        unsigned int h01, l01;
        split_pair(px * 2.f - 1.f, py * 2.f - 1.f, h01, l01);
        unsigned short h2, l2;
        split_bf16(pz * 2.f - 1.f, h2, l2);
        WR_SLOT(0, h01);
        WR_SLOT(1, (unsigned)h2 | (0x3f80u << 16));      // bias slot = 1.0
        WR_SLOT(18, l01);
        WR_SLOT(19, (unsigned)l2);
    }
    // coarse pairs: hi -> slots 2..7, lo -> slots 20..25
#pragma unroll
    for (int p = 0; p < 3; ++p) {
        u32x4 u = __builtin_nontemporal_load(&featc[(size_t)p * n + ic]);
        WR_SLOT(2 + 2 * p, u.x);
        WR_SLOT(3 + 2 * p, u.y);
        WR_SLOT(20 + 2 * p, u.z);
        WR_SLOT(21 + 2 * p, u.w);
    }
    // fine levels: slots 8..17
#pragma unroll
    for (int lvv = 0; lvv < NFINE; ++lvv) {
        unsigned int u = __builtin_nontemporal_load(&feat[(size_t)lvv * n + ic]);
        WR_SLOT(8 + lvv, u);
    }
#pragma unroll
    for (int s = 26; s < 32; ++s) WR_SLOT(s, 0u);
#undef WR_SLOT
    __syncthreads();

    // A fragments: row p = mt*16 + (lane&15), K-chunk = ks*32 + (lane>>4)*8
    bf16x8 a[4][2];
#pragma unroll
    for (int mt = 0; mt < 4; ++mt) {
        int p = mt * 16 + (lane & 15);
#pragma unroll
        for (int ks = 0; ks < 2; ++ks) {
            int off = p * 128 + ((ks * 64 + (lane >> 4) * 16) ^ ((p & 7) << 4));
            a[mt][ks] = *(const bf16x8*)(my + off);
        }
    }

    float part[4][4];
#pragma unroll
    for (int mt = 0; mt < 4; ++mt)
#pragma unroll
        for (int rr = 0; rr < 4; ++rr) part[mt][rr] = 0.f;

#pragma unroll
    for (int nt = 0; nt < 4; ++nt) {
        int col = nt * 16 + (lane & 15);
        int kb = (lane >> 4) * 8;
        bf16x8 bh0 = *(const bf16x8*)(Bh + col * 64 + kb);
        bf16x8 bh1 = *(const bf16x8*)(Bh + col * 64 + 32 + kb);
        bf16x8 bl0 = *(const bf16x8*)(Bl + col * 64 + kb);
        bf16x8 bl1 = *(const bf16x8*)(Bl + col * 64 + 32 + kb);
        float w2c = w[W2_OFF + col] * 0.01f;
#pragma unroll
        for (int mt = 0; mt < 4; ++mt) {
            f32x4 acc = {0.f, 0.f, 0.f, 0.f};
            acc = __builtin_amdgcn_mfma_f32_16x16x32_bf16(a[mt][0], bh0, acc, 0, 0, 0);
            acc = __builtin_amdgcn_mfma_f32_16x16x32_bf16(a[mt][1], bh1, acc, 0, 0, 0);
            acc = __builtin_amdgcn_mfma_f32_16x16x32_bf16(a[mt][0], bl0, acc, 0, 0, 0);
            acc = __builtin_amdgcn_mfma_f32_16x16x32_bf16(a[mt][1], bl1, acc, 0, 0, 0);
#pragma unroll
            for (int rr = 0; rr < 4; ++rr) {
                float t = 100.f * acc[rr];
                float e = __expf(-fabsf(t));
                float sp = fmaxf(t, 0.f) + __logf(1.f + e);
                part[mt][rr] = fmaf(w2c, sp, part[mt][rr]);
            }
        }
    }

    float b2v = w[B2_OFF];
#pragma unroll
    for (int mt = 0; mt < 4; ++mt) {
#pragma unroll
        for (int rr = 0; rr < 4; ++rr) {
            float v = part[mt][rr];
            v += __shfl_xor(v, 1);
            v += __shfl_xor(v, 2);
            v += __shfl_xor(v, 4);
            v += __shfl_xor(v, 8);
            if ((lane & 15) == mt) {
                int gi = base + mt * 16 + (lane >> 4) * 4 + rr;
                if (gi < n) out[sidx[gi]] = v + b2v;
            }
        }
    }
}

// fully fused fallback (tiny ws)
__global__ __launch_bounds__(256) void sdf_fused_kernel(
    const float* __restrict__ points, const float* __restrict__ table,
    const float* __restrict__ w, float* __restrict__ out, LP lp, int n) {
    int i = blockIdx.x * 256 + threadIdx.x;
    if (i >= n) return;
    float px = points[3 * i], py = points[3 * i + 1], pz = points[3 * i + 2];
    float f[35];
    f[0] = px * 2.f - 1.f; f[1] = py * 2.f - 1.f; f[2] = pz * 2.f - 1.f;
#pragma unroll
    for (int l = 0; l < NLV; ++l) {
        float scale = lp.scale[l];
        float fx = fmaf(px, scale, 0.5f), fy = fmaf(py, scale, 0.5f), fz = fmaf(pz, scale, 0.5f);
        float bx = floorf(fx), by = floorf(fy), bz = floorf(fz);
        float wx = fx - bx, wy = fy - by, wz = fz - bz;
        unsigned int ix = (unsigned int)bx, iy = (unsigned int)by, iz = (unsigned int)bz;
        const float* tl = table + (size_t)l * (TBL_SIZE * 2);
        float f0 = 0.f, f1 = 0.f;
#pragma unroll
        for (int c = 0; c < 8; ++c) {
            unsigned int qx = (c >> 2) & 1, qy = (c >> 1) & 1, qz = c & 1;
            unsigned int cx = ix + qx, cy = iy + qy, cz = iz + qz;
            unsigned int idx;
            if (l < 4) { unsigned int rr = lp.res[l]; idx = cx + cy * rr + cz * rr * rr; }
            else { idx = (cx * 1u) ^ (cy * 2654435761u) ^ (cz * 805459861u); idx &= TBL_MASK; }
            float cw = (qx ? wx : 1.f - wx) * (qy ? wy : 1.f - wy) * (qz ? wz : 1.f - wz);
            float2 g2v = *(const float2*)(tl + (size_t)idx * 2);
            f0 = fmaf(cw, g2v.x, f0); f1 = fmaf(cw, g2v.y, f1);
        }
        f[3 + 2 * l] = f0; f[4 + 2 * l] = f1;
    }
    float acc = w[B2_OFF];
#pragma unroll 4
    for (int j = 0; j < 64; ++j) {
        float hj = w[B1_OFF + j];
#pragma unroll
        for (int k = 0; k < 35; ++k) hj = fmaf(w[W1_OFF + j * 35 + k], f[k], hj);
        float t = 100.f * hj;
        float e = __expf(-fabsf(t));
        float sp = fmaxf(t, 0.f) + __logf(1.f + e);
        acc = fmaf(w[W2_OFF + j], sp * 0.01f, acc);
    }
    out[i] = acc;
}

extern "C" void kernel_launch(void* const* d_in, const int* in_sizes, int n_in,
                              void* d_out, int out_size, void* d_ws, size_t ws_size,
                              hipStream_t stream) {
    const float* points = (const float*)d_in[0];
    const float* table  = (const float*)d_in[1];
    const float* v1 = (const float*)d_in[2];
    const float* g1 = (const float*)d_in[3];
    const float* b1 = (const float*)d_in[4];
    const float* v2 = (const float*)d_in[5];
    const float* g2 = (const float*)d_in[6];
    const float* b2 = (const float*)d_in[7];
    float* out = (float*)d_out;
    float* w = (float*)d_ws;

    int n = in_sizes[0] / 3;

    LP lp;
    for (int l = 0; l < NLV; ++l) {
        double s = 32.0 * pow(1.3195079107728942, (double)l) - 1.0;
        lp.scale[l] = (float)s;
        lp.res[l] = (unsigned int)(ceil(s)) + 1u;
    }

    // ws (u32 slots): weights | tbl4[16T] | spts u2[n] | sidx[n] | hist | Bh | Bl | featc u4[3n] | feat u32[10n]
    size_t off_tbl4 = WREG;
    size_t off_spts = off_tbl4 + (size_t)NLV * TBL_SIZE;
    size_t off_sidx = off_spts + (size_t)2 * n;
    size_t off_hist = off_sidx + (size_t)n;
    size_t off_bh   = off_hist + NBINS;          // 2048 u32 (64x64 bf16)
    size_t off_bl   = off_bh + 2048;
    size_t off_fc   = off_bl + 2048;
    size_t off_fp   = off_fc + (size_t)12 * n;
    size_t need = (off_fp + (size_t)NFINE * n) * 4;

    int blocks = (n + 255) / 256;
    int bpl2 = (n + 511) / 512;   // blocks per fine-level slice (2 pts/thread)
    int hist_blocks = (NBINS + 255) / 256;
    if (ws_size >= need) {
        unsigned int* tbl4 = (unsigned int*)d_ws + off_tbl4;
        uint2* spts = (uint2*)((unsigned int*)d_ws + off_spts);
        unsigned int* sidx = (unsigned int*)d_ws + off_sidx;
        unsigned int* hist = (unsigned int*)d_ws + off_hist;
        unsigned short* Bh = (unsigned short*)((unsigned int*)d_ws + off_bh);
        unsigned short* Bl = (unsigned short*)((unsigned int*)d_ws + off_bl);
        u32x4* featc = (u32x4*)((unsigned int*)d_ws + off_fc);
        unsigned int* feat = (unsigned int*)d_ws + off_fp;

        int total_pairs = NLV * TBL_SIZE / 2;
        int cvt_blocks = (total_pairs + 255) / 256;
        prep_kernel<<<1 + hist_blocks, 256, 0, stream>>>(v1, g1, b1, v2, g2, b2, w, hist, Bh, Bl);
        aux_kernel<<<cvt_blocks + blocks, 256, 0, stream>>>(table, tbl4, hist, points, n, cvt_blocks);
        scan_kernel<<<1, 1024, 0, stream>>>(hist);
        scatter_kernel<<<blocks, 256, 0, stream>>>(points, hist, spts, sidx, n);
        hashC_kernel<<<3 * blocks, 256, 0, stream>>>(spts, tbl4, featc, lp, n, blocks);
        hashS_kernel<<<NFINE * bpl2, 256, 0, stream>>>(
            (const unsigned int*)spts, tbl4, feat, lp, n, bpl2);
        mlp3_kernel<<<blocks, 256, 0, stream>>>(spts, sidx, featc, feat, w, Bh, Bl, out, n);
    } else {
        prep_kernel<<<1, 256, 0, stream>>>(v1, g1, b1, v2, g2, b2, w, (unsigned int*)d_ws,
                                           (unsigned short*)d_ws, (unsigned short*)d_ws);
        sdf_fused_kernel<<<blocks, 256, 0, stream>>>(points, table, w, out, lp, n);
    }
}

// Round 16
// 898.617 us; speedup vs baseline: 1.0558x; 1.0268x over previous
//
#include <hip/hip_runtime.h>
#include <math.h>

#define NLV 16
#define NFINE 10
#define NSLICE 13          // 10 fine levels + 3 coarse pairs
#define TBL_SIZE (1u << 19)
#define TBL_MASK (TBL_SIZE - 1u)
#define NBINS 32768
#define QSCALE 2097152.0f   // 2^21
#define QINV   (1.0f / 2097152.0f)

// workspace float offsets (weights block, also used by fallback)
#define W1_OFF 0      // [64][35] row-major, weight-normed (f32)
#define B1_OFF 2240   // [64]
#define W2_OFF 2304   // [64]
#define B2_OFF 2368   // [1]
#define WREG   2432   // floats reserved (9728 B, 16B-aligned)

typedef __attribute__((ext_vector_type(4))) float f32x4;
typedef __attribute__((ext_vector_type(8))) short bf16x8;
typedef __attribute__((ext_vector_type(2))) unsigned int u32x2;
typedef __attribute__((ext_vector_type(4))) unsigned int u32x4;

struct LP {
    float scale[NLV];
    unsigned int res[NLV];
};

__device__ __forceinline__ unsigned int pack_bf16(float a, float b) {
    unsigned int ua = __float_as_uint(a);
    ua += 0x7fffu + ((ua >> 16) & 1u);           // RNE
    unsigned int ub = __float_as_uint(b);
    ub += 0x7fffu + ((ub >> 16) & 1u);
    return (ua >> 16) | (ub & 0xffff0000u);
}

__device__ __forceinline__ unsigned short bf16_rne(float x) {
    unsigned int u = __float_as_uint(x);
    u += 0x7fffu + ((u >> 16) & 1u);
    return (unsigned short)(u >> 16);
}

// x = hi + r exactly (hi = truncated-bf16 of x); lo = rne(r)
__device__ __forceinline__ void split_bf16(float x, unsigned short& hi, unsigned short& lo) {
    unsigned int u = __float_as_uint(x);
    hi = (unsigned short)(u >> 16);
    float r = x - __uint_as_float(u & 0xffff0000u);
    lo = bf16_rne(r);
}

__device__ __forceinline__ void split_pair(float a, float b, unsigned int& hw, unsigned int& lw) {
    unsigned short ah, al, bh, bl;
    split_bf16(a, ah, al);
    split_bf16(b, bh, bl);
    hw = (unsigned)ah | ((unsigned)bh << 16);
    lw = (unsigned)al | ((unsigned)bl << 16);
}

__device__ __forceinline__ uint2 pack_pt(float px, float py, float pz) {
    unsigned int qx = (unsigned int)fminf(px * QSCALE, 2097151.0f);
    unsigned int qy = (unsigned int)fminf(py * QSCALE, 2097151.0f);
    unsigned int qz = (unsigned int)fminf(pz * QSCALE, 2097151.0f);
    uint2 r;
    r.x = qx | (qy << 21);
    r.y = (qy >> 11) | (qz << 10);
    return r;
}

__device__ __forceinline__ void unpack_pt2(unsigned int sx, unsigned int sy,
                                           float& px, float& py, float& pz) {
    unsigned int qx = sx & 0x1FFFFFu;
    unsigned int qy = (sx >> 21) | ((sy & 0x3FFu) << 11);
    unsigned int qz = (sy >> 10) & 0x1FFFFFu;
    px = (float)qx * QINV;
    py = (float)qy * QINV;
    pz = (float)qz * QINV;
}

// merged x-pair trilinear gather for one level (dense or hashed)
__device__ __forceinline__ void gather_level(
    const unsigned int* __restrict__ tl, bool dense, unsigned int r, float scale,
    float px, float py, float pz, float& f0, float& f1) {
    float fx = fmaf(px, scale, 0.5f);
    float fy = fmaf(py, scale, 0.5f);
    float fz = fmaf(pz, scale, 0.5f);
    float bx = floorf(fx), by = floorf(fy), bz = floorf(fz);
    float wx = fx - bx, wy = fy - by, wz = fz - bz;
    unsigned int ix = (unsigned int)bx;
    unsigned int iy = (unsigned int)by;
    unsigned int iz = (unsigned int)bz;
    f0 = 0.f; f1 = 0.f;
    float omwx = 1.f - wx;
#pragma unroll
    for (int cyz = 0; cyz < 4; ++cyz) {
        unsigned int qy = cyz >> 1, qz = cyz & 1;
        unsigned int cy = iy + qy, cz = iz + qz;
        unsigned int i0, i1;
        if (dense) {
            i0 = ix + cy * r + cz * r * r;
            i1 = i0 + 1;
        } else {
            unsigned int ryz = (cy * 2654435761u) ^ (cz * 805459861u);
            i0 = (ix ^ ryz) & TBL_MASK;
            i1 = ((ix + 1u) ^ ryz) & TBL_MASK;
        }
        unsigned int sel = i0 & 1u;
        uint2 e = *(const uint2*)(tl + (i0 & ~1u));
        unsigned int lo_bits = sel ? e.y : e.x;
        unsigned int hi_bits = sel ? e.x : e.y;
        if (i1 != (i0 ^ 1u)) hi_bits = tl[i1];   // predicated: only unmerged lanes issue

        float wrow = (qy ? wy : 1.f - wy) * (qz ? wz : 1.f - wz);
        float wlo = wrow * omwx, whi = wrow * wx;
        f0 = fmaf(wlo, __uint_as_float(lo_bits << 16), f0);
        f1 = fmaf(wlo, __uint_as_float(lo_bits & 0xffff0000u), f1);
        f0 = fmaf(whi, __uint_as_float(hi_bits << 16), f0);
        f1 = fmaf(whi, __uint_as_float(hi_bits & 0xffff0000u), f1);
    }
}

// block 0: weight-norm prep + MFMA B-matrix build; blocks 1..: zero hist
// K-order (u32 slot s <-> K=2s,2s+1):
//  slot0: c0,c1  slot1: c2,BIAS(=1)  slot2+l (l=0..15): Lf0,Lf1
//  slot18: c0lo,c1lo  slot19: c2lo,0  slot20..25: zero (coarse-lo dropped)  slots26..31: 0
__global__ __launch_bounds__(256) void prep_kernel(
    const float* __restrict__ v1, const float* __restrict__ g1,
    const float* __restrict__ b1, const float* __restrict__ v2,
    const float* __restrict__ g2, const float* __restrict__ b2,
    float* __restrict__ w, unsigned int* __restrict__ hist,
    unsigned short* __restrict__ Bh, unsigned short* __restrict__ Bl) {
    int bid = blockIdx.x;
    if (bid > 0) {
        int t = (bid - 1) * 256 + threadIdx.x;
        if (t < NBINS) hist[t] = 0;
        return;
    }
    if (threadIdx.x >= 64) return;
    int j = threadIdx.x;
    float wn[35];
    float s = 0.f;
#pragma unroll
    for (int k = 0; k < 35; ++k) { float x = v1[j * 35 + k]; s += x * x; }
    float sc = g1[j] / sqrtf(s);
#pragma unroll
    for (int k = 0; k < 35; ++k) {
        wn[k] = v1[j * 35 + k] * sc;
        w[W1_OFF + j * 35 + k] = wn[k];
    }
    float b1j = b1[j];
    w[B1_OFF + j] = b1j;
    float s2 = 0.f;
#pragma unroll
    for (int i2 = 0; i2 < 64; ++i2) { float x = v2[i2]; s2 += x * x; }
    w[W2_OFF + j] = v2[j] * (g2[0] / sqrtf(s2));
    if (j == 0) w[B2_OFF] = b2[0];

#pragma unroll
    for (int k = 0; k < 64; ++k) {
        float v = 0.f;
        if (k < 3) v = wn[k];
        else if (k == 3) v = b1j;
        else if (k < 36) v = wn[k - 1];
        else if (k < 39) v = wn[k - 36];
        else if (k == 39) v = 0.f;
        else if (k < 52) v = wn[k - 37];
        unsigned short hi, lo;
        split_bf16(v, hi, lo);
        Bh[j * 64 + k] = hi;
        Bl[j * 64 + k] = lo;
    }
}

__device__ __forceinline__ unsigned int bin_key(float px, float py, float pz) {
    unsigned int ix = (unsigned int)floorf(fmaf(px, 31.f, 0.5f));
    unsigned int iy = (unsigned int)floorf(fmaf(py, 31.f, 0.5f));
    unsigned int iz = (unsigned int)floorf(fmaf(pz, 31.f, 0.5f));
    ix = min(ix, 31u); iy = min(iy, 31u); iz = min(iz, 31u);
    return ix | (iy << 5) | (iz << 10);
}

// fused: table convert | bin count (disjoint outputs)
__global__ __launch_bounds__(256) void aux_kernel(
    const float* __restrict__ table, unsigned int* __restrict__ tbl4,
    unsigned int* __restrict__ hist, const float* __restrict__ points,
    int n, int cvt_blocks) {
    int bid = blockIdx.x;
    if (bid < cvt_blocks) {
        int t = bid * 256 + threadIdx.x;
        int total_pairs = NLV * TBL_SIZE / 2;
        if (t >= total_pairs) return;
        const float4 v = *(const float4*)(table + (size_t)t * 4);
        uint2 o;
        o.x = pack_bf16(v.x, v.y);
        o.y = pack_bf16(v.z, v.w);
        *(uint2*)(tbl4 + (size_t)t * 2) = o;
    } else {
        int i = (bid - cvt_blocks) * 256 + threadIdx.x;
        if (i >= n) return;
        unsigned int k = bin_key(points[3 * i], points[3 * i + 1], points[3 * i + 2]);
        atomicAdd(&hist[k], 1u);
    }
}

// single-block exclusive scan of 32768 bins
__global__ __launch_bounds__(1024) void scan_kernel(unsigned int* __restrict__ hist) {
    __shared__ unsigned int part[1024];
    int tid = threadIdx.x;
    int base = tid * 32;
    unsigned int s = 0;
#pragma unroll
    for (int k = 0; k < 32; ++k) s += hist[base + k];
    part[tid] = s;
    __syncthreads();
    for (int d = 1; d < 1024; d <<= 1) {
        unsigned int v = (tid >= d) ? part[tid - d] : 0u;
        __syncthreads();
        part[tid] += v;
        __syncthreads();
    }
    unsigned int run = part[tid] - s;
#pragma unroll
    for (int k = 0; k < 32; ++k) {
        unsigned int t = hist[base + k];
        hist[base + k] = run;
        run += t;
    }
}

__global__ __launch_bounds__(256) void scatter_kernel(const float* __restrict__ points,
                                                      unsigned int* __restrict__ hist,
                                                      uint2* __restrict__ spts,
                                                      unsigned int* __restrict__ sidx, int n) {
    int i = blockIdx.x * 256 + threadIdx.x;
    if (i >= n) return;
    float px = points[3 * i], py = points[3 * i + 1], pz = points[3 * i + 2];
    unsigned int k = bin_key(px, py, pz);
    unsigned int pos = atomicAdd(&hist[k], 1u);
    spts[pos] = pack_pt(px, py, pz);
    sidx[pos] = (unsigned int)i;
}

// ALL gathers in one dispatch: slices 0..9 = fine levels 6..15 (2MB slab each,
// L2-resident); slices 10..12 = coarse pairs (line-shared, L1-served).
__global__ __launch_bounds__(256) void hashA_kernel(
    const uint2* __restrict__ spts, const unsigned int* __restrict__ tbl4,
    unsigned int* __restrict__ feat, u32x2* __restrict__ featc,
    LP lp, int n, int bpl) {
    int bid = blockIdx.x;
    int sl = bid / bpl;
    int i = (bid - sl * bpl) * 256 + threadIdx.x;
    if (i >= n) return;
    uint2 sp = spts[i];
    float px, py, pz;
    unpack_pt2(sp.x, sp.y, px, py, pz);

    if (sl < NFINE) {
        int level = 6 + sl;
        const unsigned int* tl = tbl4 + (size_t)level * TBL_SIZE;
        float f0, f1;
        gather_level(tl, false, 0u, lp.scale[level], px, py, pz, f0, f1);
        __builtin_nontemporal_store(pack_bf16(f0, f1), &feat[(size_t)sl * n + i]);
    } else {
        int pp = sl - NFINE;             // 0..2 -> levels (2pp, 2pp+1)
        int l0 = 2 * pp, l1 = l0 + 1;
        float a0, a1, b0, b1;
        gather_level(tbl4 + (size_t)l0 * TBL_SIZE, l0 < 4, lp.res[l0], lp.scale[l0],
                     px, py, pz, a0, a1);
        gather_level(tbl4 + (size_t)l1 * TBL_SIZE, l1 < 4, lp.res[l1], lp.scale[l1],
                     px, py, pz, b0, b1);
        u32x2 o;
        o.x = pack_bf16(a0, a1);
        o.y = pack_bf16(b0, b1);
        __builtin_nontemporal_store(o, &featc[(size_t)pp * n + i]);
    }
}

// pure MLP: feats -> LDS (swizzled) -> MFMA (hi/lo) -> softplus -> butterfly -> store
// 128 threads (2 waves), 16KB LDS -> higher occupancy than 256/32KB variant
__global__ __launch_bounds__(128) void mlp3_kernel(
    const uint2* __restrict__ spts, const unsigned int* __restrict__ sidx,
    const u32x2* __restrict__ featc, const unsigned int* __restrict__ feat,
    const float* __restrict__ w, const unsigned short* __restrict__ Bh,
    const unsigned short* __restrict__ Bl, float* __restrict__ out, int n) {
    __shared__ unsigned int lds[2][64][32];     // 8KB per wave
    int lane = threadIdx.x & 63;
    int wid = threadIdx.x >> 6;
    int base = blockIdx.x * 128 + wid * 64;
    if (base >= n) return;
    int i = base + lane;
    int ic = (i < n) ? i : (n - 1);

    uint2 sp = spts[ic];
    float px, py, pz;
    unpack_pt2(sp.x, sp.y, px, py, pz);

    char* my = (char*)&lds[wid][0][0];
    int rowoff = lane * 128;
    int swz = (lane & 7) << 4;
#define WR_SLOT(s, v) *(unsigned int*)(my + rowoff + (((s) * 4) ^ swz)) = (v)

    {
        unsigned int h01, l01;
        split_pair(px * 2.f - 1.f, py * 2.f - 1.f, h01, l01);
        unsigned short h2, l2;
        split_bf16(pz * 2.f - 1.f, h2, l2);
        WR_SLOT(0, h01);
        WR_SLOT(1, (unsigned)h2 | (0x3f80u << 16));      // bias slot = 1.0
        WR_SLOT(18, l01);
        WR_SLOT(19, (unsigned)l2);
    }
    // coarse pairs (hi only): slots 2..7
#pragma unroll
    for (int p = 0; p < 3; ++p) {
        u32x2 u = __builtin_nontemporal_load(&featc[(size_t)p * n + ic]);
        WR_SLOT(2 + 2 * p, u.x);
        WR_SLOT(3 + 2 * p, u.y);
    }
    // fine levels: slots 8..17
#pragma unroll
    for (int lvv = 0; lvv < NFINE; ++lvv) {
        unsigned int u = __builtin_nontemporal_load(&feat[(size_t)lvv * n + ic]);
        WR_SLOT(8 + lvv, u);
    }
    // slots 20..31 zero (coarse-lo dropped; tail padding)
#pragma unroll
    for (int s = 20; s < 32; ++s) {
        if (s == 18 || s == 19) continue;
        WR_SLOT(s, 0u);
    }
#undef WR_SLOT
    __syncthreads();

    // A fragments: row p = mt*16 + (lane&15), K-chunk = ks*32 + (lane>>4)*8
    bf16x8 a[4][2];
#pragma unroll
    for (int mt = 0; mt < 4; ++mt) {
        int p = mt * 16 + (lane & 15);
#pragma unroll
        for (int ks = 0; ks < 2; ++ks) {
            int off = p * 128 + ((ks * 64 + (lane >> 4) * 16) ^ ((p & 7) << 4));
            a[mt][ks] = *(const bf16x8*)(my + off);
        }
    }

    float part[4][4];
#pragma unroll
    for (int mt = 0; mt < 4; ++mt)
#pragma unroll
        for (int rr = 0; rr < 4; ++rr) part[mt][rr] = 0.f;

#pragma unroll
    for (int nt = 0; nt < 4; ++nt) {
        int col = nt * 16 + (lane & 15);
        int kb = (lane >> 4) * 8;
        bf16x8 bh0 = *(const bf16x8*)(Bh + col * 64 + kb);
        bf16x8 bh1 = *(const bf16x8*)(Bh + col * 64 + 32 + kb);
        bf16x8 bl0 = *(const bf16x8*)(Bl + col * 64 + kb);
        bf16x8 bl1 = *(const bf16x8*)(Bl + col * 64 + 32 + kb);
        float w2c = w[W2_OFF + col] * 0.01f;
#pragma unroll
        for (int mt = 0; mt < 4; ++mt) {
            f32x4 acc = {0.f, 0.f, 0.f, 0.f};
            acc = __builtin_amdgcn_mfma_f32_16x16x32_bf16(a[mt][0], bh0, acc, 0, 0, 0);
            acc = __builtin_amdgcn_mfma_f32_16x16x32_bf16(a[mt][1], bh1, acc, 0, 0, 0);
            acc = __builtin_amdgcn_mfma_f32_16x16x32_bf16(a[mt][0], bl0, acc, 0, 0, 0);
            acc = __builtin_amdgcn_mfma_f32_16x16x32_bf16(a[mt][1], bl1, acc, 0, 0, 0);
#pragma unroll
            for (int rr = 0; rr < 4; ++rr) {
                float t = 100.f * acc[rr];
                float e = __expf(-fabsf(t));
                float sp2 = fmaxf(t, 0.f) + __logf(1.f + e);
                part[mt][rr] = fmaf(w2c, sp2, part[mt][rr]);
            }
        }
    }

    float b2v = w[B2_OFF];
#pragma unroll
    for (int mt = 0; mt < 4; ++mt) {
#pragma unroll
        for (int rr = 0; rr < 4; ++rr) {
            float v = part[mt][rr];
            v += __shfl_xor(v, 1);
            v += __shfl_xor(v, 2);
            v += __shfl_xor(v, 4);
            v += __shfl_xor(v, 8);
            if ((lane & 15) == mt) {
                int gi = base + mt * 16 + (lane >> 4) * 4 + rr;
                if (gi < n) out[sidx[gi]] = v + b2v;
            }
        }
    }
}

// fully fused fallback (tiny ws)
__global__ __launch_bounds__(256) void sdf_fused_kernel(
    const float* __restrict__ points, const float* __restrict__ table,
    const float* __restrict__ w, float* __restrict__ out, LP lp, int n) {
    int i = blockIdx.x * 256 + threadIdx.x;
    if (i >= n) return;
    float px = points[3 * i], py = points[3 * i + 1], pz = points[3 * i + 2];
    float f[35];
    f[0] = px * 2.f - 1.f; f[1] = py * 2.f - 1.f; f[2] = pz * 2.f - 1.f;
#pragma unroll
    for (int l = 0; l < NLV; ++l) {
        float scale = lp.scale[l];
        float fx = fmaf(px, scale, 0.5f), fy = fmaf(py, scale, 0.5f), fz = fmaf(pz, scale, 0.5f);
        float bx = floorf(fx), by = floorf(fy), bz = floorf(fz);
        float wx = fx - bx, wy = fy - by, wz = fz - bz;
        unsigned int ix = (unsigned int)bx, iy = (unsigned int)by, iz = (unsigned int)bz;
        const float* tl = table + (size_t)l * (TBL_SIZE * 2);
        float f0 = 0.f, f1 = 0.f;
#pragma unroll
        for (int c = 0; c < 8; ++c) {
            unsigned int qx = (c >> 2) & 1, qy = (c >> 1) & 1, qz = c & 1;
            unsigned int cx = ix + qx, cy = iy + qy, cz = iz + qz;
            unsigned int idx;
            if (l < 4) { unsigned int rr = lp.res[l]; idx = cx + cy * rr + cz * rr * rr; }
            else { idx = (cx * 1u) ^ (cy * 2654435761u) ^ (cz * 805459861u); idx &= TBL_MASK; }
            float cw = (qx ? wx : 1.f - wx) * (qy ? wy : 1.f - wy) * (qz ? wz : 1.f - wz);
            float2 g2v = *(const float2*)(tl + (size_t)idx * 2);
            f0 = fmaf(cw, g2v.x, f0); f1 = fmaf(cw, g2v.y, f1);
        }
        f[3 + 2 * l] = f0; f[4 + 2 * l] = f1;
    }
    float acc = w[B2_OFF];
#pragma unroll 4
    for (int j = 0; j < 64; ++j) {
        float hj = w[B1_OFF + j];
#pragma unroll
        for (int k = 0; k < 35; ++k) hj = fmaf(w[W1_OFF + j * 35 + k], f[k], hj);
        float t = 100.f * hj;
        float e = __expf(-fabsf(t));
        float sp = fmaxf(t, 0.f) + __logf(1.f + e);
        acc = fmaf(w[W2_OFF + j], sp * 0.01f, acc);
    }
    out[i] = acc;
}

extern "C" void kernel_launch(void* const* d_in, const int* in_sizes, int n_in,
                              void* d_out, int out_size, void* d_ws, size_t ws_size,
                              hipStream_t stream) {
    const float* points = (const float*)d_in[0];
    const float* table  = (const float*)d_in[1];
    const float* v1 = (const float*)d_in[2];
    const float* g1 = (const float*)d_in[3];
    const float* b1 = (const float*)d_in[4];
    const float* v2 = (const float*)d_in[5];
    const float* g2 = (const float*)d_in[6];
    const float* b2 = (const float*)d_in[7];
    float* out = (float*)d_out;
    float* w = (float*)d_ws;

    int n = in_sizes[0] / 3;

    LP lp;
    for (int l = 0; l < NLV; ++l) {
        double s = 32.0 * pow(1.3195079107728942, (double)l) - 1.0;
        lp.scale[l] = (float)s;
        lp.res[l] = (unsigned int)(ceil(s)) + 1u;
    }

    // ws (u32 slots): weights | tbl4[16T] | spts u2[n] | sidx[n] | hist | Bh | Bl | featc u2[3n] | feat u32[10n]
    size_t off_tbl4 = WREG;
    size_t off_spts = off_tbl4 + (size_t)NLV * TBL_SIZE;
    size_t off_sidx = off_spts + (size_t)2 * n;
    size_t off_hist = off_sidx + (size_t)n;
    size_t off_bh   = off_hist + NBINS;          // 2048 u32 (64x64 bf16)
    size_t off_bl   = off_bh + 2048;
    size_t off_fc   = off_bl + 2048;
    size_t off_fp   = off_fc + (size_t)6 * n;
    size_t need = (off_fp + (size_t)NFINE * n) * 4;

    int blocks = (n + 255) / 256;
    int mblocks = (n + 127) / 128;
    int hist_blocks = (NBINS + 255) / 256;
    if (ws_size >= need) {
        unsigned int* tbl4 = (unsigned int*)d_ws + off_tbl4;
        uint2* spts = (uint2*)((unsigned int*)d_ws + off_spts);
        unsigned int* sidx = (unsigned int*)d_ws + off_sidx;
        unsigned int* hist = (unsigned int*)d_ws + off_hist;
        unsigned short* Bh = (unsigned short*)((unsigned int*)d_ws + off_bh);
        unsigned short* Bl = (unsigned short*)((unsigned int*)d_ws + off_bl);
        u32x2* featc = (u32x2*)((unsigned int*)d_ws + off_fc);
        unsigned int* feat = (unsigned int*)d_ws + off_fp;

        int total_pairs = NLV * TBL_SIZE / 2;
        int cvt_blocks = (total_pairs + 255) / 256;
        prep_kernel<<<1 + hist_blocks, 256, 0, stream>>>(v1, g1, b1, v2, g2, b2, w, hist, Bh, Bl);
        aux_kernel<<<cvt_blocks + blocks, 256, 0, stream>>>(table, tbl4, hist, points, n, cvt_blocks);
        scan_kernel<<<1, 1024, 0, stream>>>(hist);
        scatter_kernel<<<blocks, 256, 0, stream>>>(points, hist, spts, sidx, n);
        hashA_kernel<<<NSLICE * blocks, 256, 0, stream>>>(spts, tbl4, feat, featc, lp, n, blocks);
        mlp3_kernel<<<mblocks, 128, 0, stream>>>(spts, sidx, featc, feat, w, Bh, Bl, out, n);
    } else {
        prep_kernel<<<1, 256, 0, stream>>>(v1, g1, b1, v2, g2, b2, w, (unsigned int*)d_ws,
                                           (unsigned short*)d_ws, (unsigned short*)d_ws);
        sdf_fused_kernel<<<blocks, 256, 0, stream>>>(points, table, w, out, lp, n);
    }
}